// Round 4
// baseline (152.974 us; speedup 1.0000x reference)
//
#include <hip/hip_runtime.h>
#include <hip/hip_bf16.h>
#include <math.h>

// Problem constants
#define BB 64
#define QQ 100
#define NN 16
#define CC 2048            // NUM_CLASSES + 1
#define TIME_WEIGHT 2.0f
#define EOS_COEF 0.1f
#define MAGIC 0x5A5A5A5A   // != 0xAAAAAAAA harness poison, != 0

// ---------------------------------------------------------------------------
// ONE fused kernel, 1665 blocks x 256 threads, fully co-resident
// (6660 waves < 8192 wave slots -> no scheduling deadlock possible):
//   blocks 65..1664 : lse/cost producers (4 rows each). Compute logZ, the
//                     transposed cost matrix Cg[b][n][q], and the EOS-nll
//                     partial; then RELEASE flags[lb] (agent scope).
//   blocks 0..63    : JV solver for batch b. ACQUIRE-spin on the 25 flags
//                     of batch b, then run the register-resident
//                     Jonker-Volgenant (bit-exact mirror of numpy _lsa),
//                     fused CE-correction + L1-time tail; RELEASE hflag[b].
//   block 64        : finalizer. ACQUIRE-spin on hflag[0..63], fold
//                     lsepart/cpart/tpart, write the scalar loss.
// Poisoned ws (0xAA) serves as the "not ready" flag state - no memset.
// ---------------------------------------------------------------------------
__global__ __launch_bounds__(256) void detr_fused_kernel(
    const float* __restrict__ logits, const float* __restrict__ ptime,
    const int* __restrict__ labels, const float* __restrict__ tstamp,
    float* __restrict__ logZ, float* __restrict__ Cg,
    float* __restrict__ lsepart, float* __restrict__ cpart,
    float* __restrict__ tpart, int* __restrict__ flags,
    int* __restrict__ hflag, float* __restrict__ out)
{
    const int bx = blockIdx.x;
    const int t = threadIdx.x;

    __shared__ double cost[NN * QQ];    // 12.8 KB (JV blocks only)
    __shared__ float red4[4];
    __shared__ int qsl[NN];

    // =======================================================================
    // LSE / cost producer path
    // =======================================================================
    if (bx >= BB + 1) {
        const int lb = bx - (BB + 1);              // 0..1599
        const int wave = t >> 6;
        const int lane = t & 63;
        const int bq = lb * 4 + wave;              // < 6400
        const int b = bq / QQ, q = bq % QQ;
        const float4* row4 = (const float4*)(logits + (size_t)bq * CC);

        float4 v[8];
        #pragma unroll
        for (int c = 0; c < 8; ++c) v[c] = row4[c * 64 + lane];

        float m = -INFINITY;
        #pragma unroll
        for (int c = 0; c < 8; ++c)
            m = fmaxf(m, fmaxf(fmaxf(v[c].x, v[c].y), fmaxf(v[c].z, v[c].w)));
        #pragma unroll
        for (int s = 1; s < 64; s <<= 1) m = fmaxf(m, __shfl_xor(m, s, 64));

        float sum = 0.f;
        #pragma unroll
        for (int c = 0; c < 8; ++c)
            sum += expf(v[c].x - m) + expf(v[c].y - m) +
                   expf(v[c].z - m) + expf(v[c].w - m);
        #pragma unroll
        for (int s = 1; s < 64; s <<= 1) sum += __shfl_xor(sum, s, 64);

        const float lz = m + logf(sum);
        if (lane == 0) logZ[bq] = lz;

        const float pt = ptime[bq];
        if (lane < NN) {
            int lab = labels[b * NN + lane];
            float lg = logits[(size_t)bq * CC + lab];   // L1-hot (same row)
            float cc = -expf(lg - lz);
            float ct = fabsf(pt - tstamp[b * NN + lane]);
            float val = cc + TIME_WEIGHT * ct;
            if (isnan(val)) val = 100.0f;
            else if (isinf(val)) val = (val > 0.f) ? 100.0f : -100.0f;
            Cg[((size_t)b * NN + lane) * QQ + q] = val;
        }

        if (lane == 0) red4[wave] = lz - logits[(size_t)bq * CC];
        __syncthreads();   // also drains each wave's global stores (vmcnt 0)
        if (t == 0) {
            lsepart[lb] = red4[0] + red4[1] + red4[2] + red4[3];
            __hip_atomic_store(&flags[lb], MAGIC, __ATOMIC_RELEASE,
                               __HIP_MEMORY_SCOPE_AGENT);
        }
        return;
    }

    // =======================================================================
    // Finalizer path
    // =======================================================================
    if (bx == BB) {
        if (t < 64) {
            int ok = 0;
            for (;;) {
                if (!ok) ok = (__hip_atomic_load(&hflag[t], __ATOMIC_ACQUIRE,
                                                 __HIP_MEMORY_SCOPE_AGENT) == MAGIC);
                if (__all(ok)) break;
                __builtin_amdgcn_s_sleep(1);
            }
            float r0 = 0.f;
            #pragma unroll
            for (int k = 0; k < 25; ++k) r0 += lsepart[t + 64 * k];  // 1600=64*25
            float c = cpart[t];
            float tl = tpart[t];
            #pragma unroll
            for (int s = 1; s < 64; s <<= 1) {
                r0 += __shfl_xor(r0, s, 64);
                c  += __shfl_xor(c, s, 64);
                tl += __shfl_xor(tl, s, 64);
            }
            if (t == 0) {
                const float sum_w = (float)(BB * NN) * 1.0f
                                  + (float)(BB * (QQ - NN)) * EOS_COEF;  // 1561.6
                float loss_ce = (EOS_COEF * r0 + c) / sum_w;
                float loss_t  = tl / (float)(BB * NN);
                out[0] = loss_ce + TIME_WEIGHT * loss_t;
            }
        }
        return;
    }

    // =======================================================================
    // JV solver path (batch b = bx)
    // =======================================================================
    const int b = bx;

    if (t < 64) {          // wave 0: wait for this batch's 25 producer blocks
        int ok = (t >= 25);
        for (;;) {
            if (!ok) ok = (__hip_atomic_load(&flags[b * 25 + t], __ATOMIC_ACQUIRE,
                                             __HIP_MEMORY_SCOPE_AGENT) == MAGIC);
            if (__all(ok)) break;
            __builtin_amdgcn_s_sleep(1);
        }
    }
    __syncthreads();

    for (int idx = t; idx < NN * QQ; idx += 256)
        cost[idx] = (double)Cg[(size_t)b * NN * QQ + idx];
    __syncthreads();

    // --- register-resident JV on wave 0 (bit-exact mirror of numpy _lsa) ---
    const int jc0 = t + 1;
    const int jc1 = t + 65;
    const bool has2 = (jc1 <= QQ);
    double v0 = 0.0, v1 = 0.0;
    double ureg = 0.0;                  // lane r holds u[r+1] (lanes 0..15)
    int preg0 = 0, preg1 = 0;           // p[jc0], p[jc1] (0 = free)
    const double INF = __builtin_inf();

    if (t < 64) {
        for (int i = 1; i <= NN; ++i) {
            double minv0 = INF, minv1 = INF;
            bool used0 = false, used1 = false;
            int way0 = 0, way1 = 0;
            bool inTree = (t == i - 1);
            int j0 = 0;
            int i0 = i;

            while (true) {
                used0 |= (j0 == jc0);
                used1 |= (j0 == jc1);
                inTree = inTree || (t == i0 - 1);
                const double u_i0 = __shfl(ureg, i0 - 1, 64);
                const double* crow = &cost[(i0 - 1) * QQ];

                double bestv = INF;
                int bestj = 0x7FFFFFFF;
                if (!used0) {
                    double cur = crow[jc0 - 1] - u_i0 - v0;
                    if (cur < minv0) { minv0 = cur; way0 = j0; }
                    bestv = minv0; bestj = jc0;
                }
                if (has2 && !used1) {
                    double cur = crow[jc1 - 1] - u_i0 - v1;
                    if (cur < minv1) { minv1 = cur; way1 = j0; }
                    if (minv1 < bestv) { bestv = minv1; bestj = jc1; }
                }
                #pragma unroll
                for (int s = 1; s < 64; s <<= 1) {
                    double ov = __shfl_xor(bestv, s, 64);
                    int oj = __shfl_xor(bestj, s, 64);
                    if (ov < bestv || (ov == bestv && oj < bestj)) { bestv = ov; bestj = oj; }
                }
                const double delta = bestv;
                const int j1 = bestj;

                if (inTree) ureg += delta;
                if (used0) v0 -= delta; else minv0 -= delta;
                if (has2) { if (used1) v1 -= delta; else minv1 -= delta; }

                j0 = j1;
                int psrc = (j0 <= 64) ? preg0 : preg1;
                int plane = (j0 <= 64) ? (j0 - 1) : (j0 - 65);
                int pj = __shfl(psrc, plane, 64);
                if (pj == 0) break;
                i0 = pj;
            }

            while (j0 != 0) {           // augment (uniform walk)
                int wsrc = (j0 <= 64) ? way0 : way1;
                int wlane = (j0 <= 64) ? (j0 - 1) : (j0 - 65);
                int jn = __shfl(wsrc, wlane, 64);
                int pv;
                if (jn == 0) pv = i;
                else {
                    int psrc = (jn <= 64) ? preg0 : preg1;
                    int plane = (jn <= 64) ? (jn - 1) : (jn - 65);
                    pv = __shfl(psrc, plane, 64);
                }
                if (j0 == jc0) preg0 = pv;
                if (has2 && j0 == jc1) preg1 = pv;
                j0 = jn;
            }
        }

        if (preg0 > 0) qsl[preg0 - 1] = jc0 - 1;
        if (has2 && preg1 > 0) qsl[preg1 - 1] = jc1 - 1;
    }
    __syncthreads();

    if (t < 64) {
        float corr = 0.f, tl = 0.f;
        if (t < NN) {
            int qcol = qsl[t];
            int lab = labels[b * NN + t];
            int bq = b * QQ + qcol;
            float lz = logZ[bq];
            float lgm = logits[(size_t)bq * CC + lab];
            float lg0 = logits[(size_t)bq * CC];
            corr = (lz - lgm) - EOS_COEF * (lz - lg0);
            tl = fabsf(ptime[bq] - tstamp[b * NN + t]);
        }
        #pragma unroll
        for (int s = 1; s < 64; s <<= 1) {
            corr += __shfl_xor(corr, s, 64);
            tl   += __shfl_xor(tl, s, 64);
        }
        if (t == 0) {
            cpart[b] = corr;
            tpart[b] = tl;
            __hip_atomic_store(&hflag[b], MAGIC, __ATOMIC_RELEASE,
                               __HIP_MEMORY_SCOPE_AGENT);
        }
    }
}

// ---------------------------------------------------------------------------
// Workspace layout (bytes):
//   [0,      25600)  : float logZ[6400]
//   [25600, 435200)  : float Cg[64*16*100]
//   [435200, 441600) : float lsepart[1600]
//   [441600, 441856) : float cpart[64]
//   [441856, 442112) : float tpart[64]
//   [442112, 448512) : int   flags[1600]   (0xAA poison == "not ready")
//   [448512, 448768) : int   hflag[64]
// ---------------------------------------------------------------------------
extern "C" void kernel_launch(void* const* d_in, const int* in_sizes, int n_in,
                              void* d_out, int out_size, void* d_ws, size_t ws_size,
                              hipStream_t stream) {
    const float* logits = (const float*)d_in[0];   // [B,Q,2048]
    const float* ptime  = (const float*)d_in[1];   // [B,Q,1]
    const int*   labels = (const int*)d_in[2];     // [B,N]
    const float* tstamp = (const float*)d_in[3];   // [B,N,1]
    float* out = (float*)d_out;

    char* ws = (char*)d_ws;
    float* logZ    = (float*)ws;
    float* Cg      = (float*)(ws + 25600);
    float* lsepart = (float*)(ws + 435200);
    float* cpart   = (float*)(ws + 441600);
    float* tpart   = (float*)(ws + 441856);
    int*   flags   = (int*)(ws + 442112);
    int*   hflag   = (int*)(ws + 448512);

    detr_fused_kernel<<<1600 + BB + 1, 256, 0, stream>>>(
        logits, ptime, labels, tstamp, logZ, Cg, lsepart, cpart, tpart,
        flags, hflag, out);
}

// Round 5
// 113.173 us; speedup vs baseline: 1.3517x; 1.3517x over previous
//
#include <hip/hip_runtime.h>
#include <hip/hip_bf16.h>
#include <math.h>

// Problem constants
#define BB 64
#define QQ 100
#define NN 16
#define CC 2048            // NUM_CLASSES + 1
#define TIME_WEIGHT 2.0f
#define EOS_COEF 0.1f

__device__ __forceinline__ double readlane_d(double x, int lane) {
    int lo = __builtin_amdgcn_readlane(__double2loint(x), lane);
    int hi = __builtin_amdgcn_readlane(__double2hiint(x), lane);
    return __hiloint2double(hi, lo);
}

// ---------------------------------------------------------------------------
// Kernel 1: per (b,q) row (one wave each):
//   logZ[b,q] = logsumexp(logits[b,q,:])
//   Cg[b][n][q] = -softmax[label_n] + 2*|pt - ts_n|   (transposed cost matrix)
//   lsepart[block] = sum over 4 rows of (logZ - logit[class 0])   [EOS nll]
// Block 0 additionally zero-inits the atomic accumulators for kernel 2.
// ---------------------------------------------------------------------------
__global__ __launch_bounds__(256) void lse_cost_kernel(
    const float* __restrict__ logits, const float* __restrict__ ptime,
    const int* __restrict__ labels, const float* __restrict__ tstamp,
    float* __restrict__ logZ, float* __restrict__ Cg,
    float* __restrict__ lsepart, float* __restrict__ sums, int* __restrict__ counter)
{
    if (blockIdx.x == 0 && threadIdx.x == 0) {
        sums[0] = 0.f; sums[1] = 0.f; *counter = 0;
    }
    const int wave = threadIdx.x >> 6;
    const int lane = threadIdx.x & 63;
    const int bq = blockIdx.x * 4 + wave;          // < 6400
    const int b = bq / QQ, q = bq % QQ;
    const float4* row4 = (const float4*)(logits + (size_t)bq * CC);

    float4 v[8];
    #pragma unroll
    for (int c = 0; c < 8; ++c) v[c] = row4[c * 64 + lane];

    float m = -INFINITY;
    #pragma unroll
    for (int c = 0; c < 8; ++c)
        m = fmaxf(m, fmaxf(fmaxf(v[c].x, v[c].y), fmaxf(v[c].z, v[c].w)));
    #pragma unroll
    for (int s = 1; s < 64; s <<= 1) m = fmaxf(m, __shfl_xor(m, s, 64));

    float sum = 0.f;
    #pragma unroll
    for (int c = 0; c < 8; ++c)
        sum += expf(v[c].x - m) + expf(v[c].y - m) +
               expf(v[c].z - m) + expf(v[c].w - m);
    #pragma unroll
    for (int s = 1; s < 64; s <<= 1) sum += __shfl_xor(sum, s, 64);

    const float lz = m + logf(sum);
    if (lane == 0) logZ[bq] = lz;

    // cost-matrix entries (lanes 0..15: one target each)
    const float pt = ptime[bq];
    if (lane < NN) {
        int lab = labels[b * NN + lane];
        float lg = logits[(size_t)bq * CC + lab];     // L1-hot gather (same row)
        float cc = -expf(lg - lz);
        float ct = fabsf(pt - tstamp[b * NN + lane]);
        float val = cc + TIME_WEIGHT * ct;
        if (isnan(val)) val = 100.0f;
        else if (isinf(val)) val = (val > 0.f) ? 100.0f : -100.0f;
        Cg[((size_t)b * NN + lane) * QQ + q] = val;
    }

    // EOS nll partial: nll0 = logZ - logit[class 0]
    __shared__ float red[4];
    if (lane == 0) red[wave] = lz - logits[(size_t)bq * CC];
    __syncthreads();
    if (threadIdx.x == 0)
        lsepart[blockIdx.x] = red[0] + red[1] + red[2] + red[3];
}

// ---------------------------------------------------------------------------
// Kernel 2: Jonker-Volgenant assignment, one wave per batch, register-
// resident state. Critical-path version:
//   - uniform-index broadcasts (u[i0], p[j0], way[j0]) via v_readlane
//   - argmin: per-lane candidates -> fmin xor-butterfly within 32-lane
//     halves (5 stages) -> cross-half combine via 2 readlanes -> ballot +
//     ctz for the winning column. Since all lane-first columns (1..64) are
//     lower than all lane-second columns (65..100), "ballot A first, else
//     ballot B, lowest set lane" == np.argmin lowest-index tie-break.
//   - fmin returns a bit-exact member of the candidate set, so the
//     equality ballot identifies exactly the reference argmin.
// Fused tail: CE correction + L1 time partials -> device atomics; last of
// the 64 blocks folds lsepart and writes the final scalar loss.
// ---------------------------------------------------------------------------
__global__ __launch_bounds__(64) void hungarian_kernel(
    const float* __restrict__ Cg, const float* __restrict__ logits,
    const float* __restrict__ ptime, const int* __restrict__ labels,
    const float* __restrict__ tstamp, const float* __restrict__ logZ,
    const float* __restrict__ lsepart, float* __restrict__ sums,
    int* __restrict__ counter, float* __restrict__ out)
{
    const int b = blockIdx.x;
    const int t = threadIdx.x;

    __shared__ double cost[NN * QQ];    // 12.8 KB
    __shared__ int qsl[NN];

    for (int idx = t; idx < NN * QQ; idx += 64)
        cost[idx] = (double)Cg[(size_t)b * NN * QQ + idx];
    __syncthreads();

    // Lane t owns columns jc0 = t+1 and (if <=100) jc1 = t+65 (1-based).
    const int jc0 = t + 1;
    const int jc1 = t + 65;
    const bool has2 = (jc1 <= QQ);
    double v0 = 0.0, v1 = 0.0;          // column potentials (owned)
    double ureg = 0.0;                  // lane r holds u[r+1] (lanes 0..15)
    int preg0 = 0, preg1 = 0;           // p[jc0], p[jc1] (0 = free)
    const double INF = __builtin_inf();

    for (int i = 1; i <= NN; ++i) {
        double minv0 = INF, minv1 = INF;
        bool used0 = false, used1 = false;
        int way0 = 0, way1 = 0;
        bool inTree = (t == i - 1);     // p[0] = i enters the tree at start
        int j0 = 0;
        int i0 = i;                      // p[0]

        while (true) {
            used0 |= (j0 == jc0);
            used1 |= (j0 == jc1);
            inTree = inTree || (t == i0 - 1);
            const double u_i0 = readlane_d(ureg, i0 - 1);
            const double* crow = &cost[(i0 - 1) * QQ];

            if (!used0) {
                double cur = crow[jc0 - 1] - u_i0 - v0;
                if (cur < minv0) { minv0 = cur; way0 = j0; }
            }
            if (has2 && !used1) {
                double cur = crow[jc1 - 1] - u_i0 - v1;
                if (cur < minv1) { minv1 = cur; way1 = j0; }
            }

            // value-only min reduction
            double m0 = used0 ? INF : minv0;
            double m1 = (has2 && !used1) ? minv1 : INF;
            double gmin = fmin(m0, m1);
            #pragma unroll
            for (int s = 1; s < 32; s <<= 1)
                gmin = fmin(gmin, __shfl_xor(gmin, s, 64));
            {
                double h0 = readlane_d(gmin, 0);
                double h1 = readlane_d(gmin, 32);
                gmin = fmin(h0, h1);
            }
            // winning column: ballot A (cols 1..64) has priority, then B
            unsigned long long A  = __ballot(!used0 && (minv0 == gmin));
            unsigned long long Bm = __ballot(has2 && !used1 && (minv1 == gmin));
            int j1 = (A != 0ull) ? ((int)__builtin_ctzll(A) + 1)
                                 : ((int)__builtin_ctzll(Bm) + 65);
            const double delta = gmin;

            if (inTree) ureg += delta;                   // u[p[used]] += delta
            if (used0) v0 -= delta; else minv0 -= delta;
            if (has2) { if (used1) v1 -= delta; else minv1 -= delta; }

            j0 = j1;
            int pj = (j0 <= 64) ? __builtin_amdgcn_readlane(preg0, j0 - 1)
                                : __builtin_amdgcn_readlane(preg1, j0 - 65);
            if (pj == 0) break;
            i0 = pj;
        }

        // augment along the alternating path (uniform walk)
        while (j0 != 0) {
            int jn = (j0 <= 64) ? __builtin_amdgcn_readlane(way0, j0 - 1)
                                : __builtin_amdgcn_readlane(way1, j0 - 65);
            int pv;
            if (jn == 0) pv = i;
            else pv = (jn <= 64) ? __builtin_amdgcn_readlane(preg0, jn - 1)
                                 : __builtin_amdgcn_readlane(preg1, jn - 65);
            if (j0 == jc0) preg0 = pv;
            if (has2 && j0 == jc1) preg1 = pv;
            j0 = jn;
        }
    }

    // extract matches: qsl[target row] = column
    if (preg0 > 0) qsl[preg0 - 1] = jc0 - 1;
    if (has2 && preg1 > 0) qsl[preg1 - 1] = jc1 - 1;
    __syncthreads();

    // fused tail: CE correction + time-loss partials for this batch
    float corr = 0.f, tl = 0.f;
    if (t < NN) {
        int qcol = qsl[t];
        int lab = labels[b * NN + t];
        int bq = b * QQ + qcol;
        float lz = logZ[bq];
        float lgm = logits[(size_t)bq * CC + lab];
        float lg0 = logits[(size_t)bq * CC];
        corr = (lz - lgm) - EOS_COEF * (lz - lg0);
        tl = fabsf(ptime[bq] - tstamp[b * NN + t]);
    }
    #pragma unroll
    for (int s = 1; s < 64; s <<= 1) {
        corr += __shfl_xor(corr, s, 64);
        tl   += __shfl_xor(tl, s, 64);
    }

    int old = 0;
    if (t == 0) {
        atomicAdd(&sums[0], corr);
        atomicAdd(&sums[1], tl);
        __threadfence();                 // release partials before counter bump
        old = atomicAdd(counter, 1);
    }
    old = __shfl(old, 0, 64);
    if (old == BB - 1) {                 // last block finalizes
        __threadfence();                 // acquire others' partials
        float r0 = 0.f;
        #pragma unroll
        for (int k = 0; k < 25; ++k) r0 += lsepart[t + 64 * k];   // 1600 = 64*25
        #pragma unroll
        for (int s = 1; s < 64; s <<= 1) r0 += __shfl_xor(r0, s, 64);
        if (t == 0) {
            float s0 = atomicAdd(&sums[0], 0.0f);
            float s1 = atomicAdd(&sums[1], 0.0f);
            const float sum_w = (float)(BB * NN) * 1.0f
                              + (float)(BB * (QQ - NN)) * EOS_COEF;   // 1561.6
            float loss_ce = (EOS_COEF * r0 + s0) / sum_w;
            float loss_t  = s1 / (float)(BB * NN);
            out[0] = loss_ce + TIME_WEIGHT * loss_t;
        }
    }
}

// ---------------------------------------------------------------------------
// Workspace layout (bytes):
//   [0,      25600)  : float logZ[6400]
//   [25600, 435200)  : float Cg[64*16*100]
//   [435200, 441600) : float lsepart[1600]
//   [441600, 441608) : float sums[2]   {ce_corr, time}   (zeroed by kernel 1)
//   [441608, 441612) : int   counter                     (zeroed by kernel 1)
// ---------------------------------------------------------------------------
extern "C" void kernel_launch(void* const* d_in, const int* in_sizes, int n_in,
                              void* d_out, int out_size, void* d_ws, size_t ws_size,
                              hipStream_t stream) {
    const float* logits = (const float*)d_in[0];   // [B,Q,2048]
    const float* ptime  = (const float*)d_in[1];   // [B,Q,1]
    const int*   labels = (const int*)d_in[2];     // [B,N]
    const float* tstamp = (const float*)d_in[3];   // [B,N,1]
    float* out = (float*)d_out;

    char* ws = (char*)d_ws;
    float* logZ    = (float*)ws;
    float* Cg      = (float*)(ws + 25600);
    float* lsepart = (float*)(ws + 435200);
    float* sums    = (float*)(ws + 441600);
    int*   counter = (int*)(ws + 441608);

    lse_cost_kernel<<<1600, 256, 0, stream>>>(logits, ptime, labels, tstamp,
                                              logZ, Cg, lsepart, sums, counter);
    hungarian_kernel<<<BB, 64, 0, stream>>>(Cg, logits, ptime, labels, tstamp,
                                            logZ, lsepart, sums, counter, out);
}

// Round 6
// 110.095 us; speedup vs baseline: 1.3895x; 1.0280x over previous
//
#include <hip/hip_runtime.h>
#include <hip/hip_bf16.h>
#include <math.h>

// Problem constants
#define BB 64
#define QQ 100
#define NN 16
#define CC 2048            // NUM_CLASSES + 1
#define TIME_WEIGHT 2.0f
#define EOS_COEF 0.1f

__device__ __forceinline__ double readlane_d(double x, int lane) {
    int lo = __builtin_amdgcn_readlane(__double2loint(x), lane);
    int hi = __builtin_amdgcn_readlane(__double2hiint(x), lane);
    return __hiloint2double(hi, lo);
}

// ---------------------------------------------------------------------------
// Kernel 1: per (b,q) row (one wave each):
//   logZ[b,q] = logsumexp(logits[b,q,:])
//   Cg[b][n][q] = -softmax[label_n] + 2*|pt - ts_n|   (transposed cost matrix)
//   lsepart[block] = sum over 4 rows of (logZ - logit[class 0])   [EOS nll]
// Block 0 additionally zero-inits the atomic accumulators for kernel 2.
// ---------------------------------------------------------------------------
__global__ __launch_bounds__(256) void lse_cost_kernel(
    const float* __restrict__ logits, const float* __restrict__ ptime,
    const int* __restrict__ labels, const float* __restrict__ tstamp,
    float* __restrict__ logZ, float* __restrict__ Cg,
    float* __restrict__ lsepart, float* __restrict__ sums, int* __restrict__ counter)
{
    if (blockIdx.x == 0 && threadIdx.x == 0) {
        sums[0] = 0.f; sums[1] = 0.f; *counter = 0;
    }
    const int wave = threadIdx.x >> 6;
    const int lane = threadIdx.x & 63;
    const int bq = blockIdx.x * 4 + wave;          // < 6400
    const int b = bq / QQ, q = bq % QQ;
    const float4* row4 = (const float4*)(logits + (size_t)bq * CC);

    float4 v[8];
    #pragma unroll
    for (int c = 0; c < 8; ++c) v[c] = row4[c * 64 + lane];

    float m = -INFINITY;
    #pragma unroll
    for (int c = 0; c < 8; ++c)
        m = fmaxf(m, fmaxf(fmaxf(v[c].x, v[c].y), fmaxf(v[c].z, v[c].w)));
    #pragma unroll
    for (int s = 1; s < 64; s <<= 1) m = fmaxf(m, __shfl_xor(m, s, 64));

    float sum = 0.f;
    #pragma unroll
    for (int c = 0; c < 8; ++c)
        sum += expf(v[c].x - m) + expf(v[c].y - m) +
               expf(v[c].z - m) + expf(v[c].w - m);
    #pragma unroll
    for (int s = 1; s < 64; s <<= 1) sum += __shfl_xor(sum, s, 64);

    const float lz = m + logf(sum);
    if (lane == 0) logZ[bq] = lz;

    // cost-matrix entries (lanes 0..15: one target each)
    const float pt = ptime[bq];
    if (lane < NN) {
        int lab = labels[b * NN + lane];
        float lg = logits[(size_t)bq * CC + lab];     // L1-hot gather (same row)
        float cc = -expf(lg - lz);
        float ct = fabsf(pt - tstamp[b * NN + lane]);
        float val = cc + TIME_WEIGHT * ct;
        if (isnan(val)) val = 100.0f;
        else if (isinf(val)) val = (val > 0.f) ? 100.0f : -100.0f;
        Cg[((size_t)b * NN + lane) * QQ + q] = val;
    }

    // EOS nll partial: nll0 = logZ - logit[class 0]
    __shared__ float red[4];
    if (lane == 0) red[wave] = lz - logits[(size_t)bq * CC];
    __syncthreads();
    if (threadIdx.x == 0)
        lsepart[blockIdx.x] = red[0] + red[1] + red[2] + red[3];
}

// ---------------------------------------------------------------------------
// Kernel 2: Jonker-Volgenant assignment, one wave per batch, FULLY register-
// resident: the 16x100 cost matrix lives in per-lane registers (lane t holds
// all 16 rows of its two owned columns, 32 doubles), selected per-iteration
// by a wave-uniform 16-way switch (i0 is scalar) - no LDS on the critical
// path. Min-reduction: 4 DPP xor stages (within 16-lane rows) + 4 readlanes
// + 3 v_min_f64 (no ds_swizzle). Winning column via equality ballots with
// cols 1..64 prioritized over 65..100 == np.argmin lowest-index tie-break
// (fmin returns a bit-exact member of the candidate set). All double
// arithmetic operation-identical to the numpy reference _lsa.
// Fused tail: CE correction + L1 time partials -> device atomics; last of
// the 64 blocks folds lsepart and writes the final scalar loss.
// ---------------------------------------------------------------------------
__global__ __launch_bounds__(64) void hungarian_kernel(
    const float* __restrict__ Cg, const float* __restrict__ logits,
    const float* __restrict__ ptime, const int* __restrict__ labels,
    const float* __restrict__ tstamp, const float* __restrict__ logZ,
    const float* __restrict__ lsepart, float* __restrict__ sums,
    int* __restrict__ counter, float* __restrict__ out)
{
    const int b = blockIdx.x;
    const int t = threadIdx.x;

    __shared__ int qsl[NN];

    // Lane t owns columns jc0 = t+1 and (if <=100) jc1 = t+65 (1-based).
    const int jc0 = t + 1;
    const int jc1 = t + 65;
    const bool has2 = (jc1 <= QQ);
    const int t2 = has2 ? (t + 64) : t;            // clamp keeps loads in-bounds

    // cost columns in registers: c0r[r] = cost[r][jc0-1], c1r[r] = cost[r][jc1-1]
    const float* cgb = Cg + (size_t)b * NN * QQ;
    double c0r[NN], c1r[NN];
    #pragma unroll
    for (int r = 0; r < NN; ++r) {
        c0r[r] = (double)cgb[r * QQ + t];
        c1r[r] = (double)cgb[r * QQ + t2];
    }

    double v0 = 0.0, v1 = 0.0;          // column potentials (owned)
    double ureg = 0.0;                  // lane r holds u[r+1] (lanes 0..15)
    int preg0 = 0, preg1 = 0;           // p[jc0], p[jc1] (0 = free)
    const double INF = __builtin_inf();

    for (int i = 1; i <= NN; ++i) {
        double minv0 = INF, minv1 = INF;
        bool used0 = false, used1 = false;
        int way0 = 0, way1 = 0;
        bool inTree = (t == i - 1);     // p[0] = i enters the tree at start
        int j0 = 0;
        int i0 = i;                      // p[0]

        while (true) {
            used0 |= (j0 == jc0);
            used1 |= (j0 == jc1);
            inTree = inTree || (t == i0 - 1);
            const double u_i0 = readlane_d(ureg, i0 - 1);

            // wave-uniform register select of this row's two cost entries
            double ca, cb;
            switch (i0 - 1) {
                case 0:  ca = c0r[0];  cb = c1r[0];  break;
                case 1:  ca = c0r[1];  cb = c1r[1];  break;
                case 2:  ca = c0r[2];  cb = c1r[2];  break;
                case 3:  ca = c0r[3];  cb = c1r[3];  break;
                case 4:  ca = c0r[4];  cb = c1r[4];  break;
                case 5:  ca = c0r[5];  cb = c1r[5];  break;
                case 6:  ca = c0r[6];  cb = c1r[6];  break;
                case 7:  ca = c0r[7];  cb = c1r[7];  break;
                case 8:  ca = c0r[8];  cb = c1r[8];  break;
                case 9:  ca = c0r[9];  cb = c1r[9];  break;
                case 10: ca = c0r[10]; cb = c1r[10]; break;
                case 11: ca = c0r[11]; cb = c1r[11]; break;
                case 12: ca = c0r[12]; cb = c1r[12]; break;
                case 13: ca = c0r[13]; cb = c1r[13]; break;
                case 14: ca = c0r[14]; cb = c1r[14]; break;
                default: ca = c0r[15]; cb = c1r[15]; break;
            }

            if (!used0) {
                double cur = ca - u_i0 - v0;
                if (cur < minv0) { minv0 = cur; way0 = j0; }
            }
            if (has2 && !used1) {
                double cur = cb - u_i0 - v1;
                if (cur < minv1) { minv1 = cur; way1 = j0; }
            }

            // value-only min reduction: 4 DPP stages within 16-lane rows,
            // then 4 readlanes + 3 fmin across rows.
            double m0 = used0 ? INF : minv0;
            double m1 = (has2 && !used1) ? minv1 : INF;
            double gmin = fmin(m0, m1);
            #pragma unroll
            for (int s = 1; s < 16; s <<= 1)
                gmin = fmin(gmin, __shfl_xor(gmin, s, 64));
            {
                double h0 = readlane_d(gmin, 0);
                double h1 = readlane_d(gmin, 16);
                double h2 = readlane_d(gmin, 32);
                double h3 = readlane_d(gmin, 48);
                gmin = fmin(fmin(h0, h1), fmin(h2, h3));
            }
            // winning column: ballot A (cols 1..64) has priority, then B
            unsigned long long A  = __ballot(!used0 && (minv0 == gmin));
            unsigned long long Bm = __ballot(has2 && !used1 && (minv1 == gmin));
            int j1 = (A != 0ull) ? ((int)__builtin_ctzll(A) + 1)
                                 : ((int)__builtin_ctzll(Bm) + 65);
            const double delta = gmin;

            if (inTree) ureg += delta;                   // u[p[used]] += delta
            if (used0) v0 -= delta; else minv0 -= delta;
            if (has2) { if (used1) v1 -= delta; else minv1 -= delta; }

            j0 = j1;
            int pj = (j0 <= 64) ? __builtin_amdgcn_readlane(preg0, j0 - 1)
                                : __builtin_amdgcn_readlane(preg1, j0 - 65);
            if (pj == 0) break;
            i0 = pj;
        }

        // augment along the alternating path (uniform walk)
        while (j0 != 0) {
            int jn = (j0 <= 64) ? __builtin_amdgcn_readlane(way0, j0 - 1)
                                : __builtin_amdgcn_readlane(way1, j0 - 65);
            int pv;
            if (jn == 0) pv = i;
            else pv = (jn <= 64) ? __builtin_amdgcn_readlane(preg0, jn - 1)
                                 : __builtin_amdgcn_readlane(preg1, jn - 65);
            if (j0 == jc0) preg0 = pv;
            if (has2 && j0 == jc1) preg1 = pv;
            j0 = jn;
        }
    }

    // extract matches: qsl[target row] = column
    if (preg0 > 0) qsl[preg0 - 1] = jc0 - 1;
    if (has2 && preg1 > 0) qsl[preg1 - 1] = jc1 - 1;
    __syncthreads();

    // fused tail: CE correction + time-loss partials for this batch
    float corr = 0.f, tl = 0.f;
    if (t < NN) {
        int qcol = qsl[t];
        int lab = labels[b * NN + t];
        int bq = b * QQ + qcol;
        float lz = logZ[bq];
        float lgm = logits[(size_t)bq * CC + lab];
        float lg0 = logits[(size_t)bq * CC];
        corr = (lz - lgm) - EOS_COEF * (lz - lg0);
        tl = fabsf(ptime[bq] - tstamp[b * NN + t]);
    }
    #pragma unroll
    for (int s = 1; s < 64; s <<= 1) {
        corr += __shfl_xor(corr, s, 64);
        tl   += __shfl_xor(tl, s, 64);
    }

    int old = 0;
    if (t == 0) {
        atomicAdd(&sums[0], corr);
        atomicAdd(&sums[1], tl);
        __threadfence();                 // release partials before counter bump
        old = atomicAdd(counter, 1);
    }
    old = __shfl(old, 0, 64);
    if (old == BB - 1) {                 // last block finalizes
        __threadfence();                 // acquire others' partials
        float r0 = 0.f;
        #pragma unroll
        for (int k = 0; k < 25; ++k) r0 += lsepart[t + 64 * k];   // 1600 = 64*25
        #pragma unroll
        for (int s = 1; s < 64; s <<= 1) r0 += __shfl_xor(r0, s, 64);
        if (t == 0) {
            float s0 = atomicAdd(&sums[0], 0.0f);
            float s1 = atomicAdd(&sums[1], 0.0f);
            const float sum_w = (float)(BB * NN) * 1.0f
                              + (float)(BB * (QQ - NN)) * EOS_COEF;   // 1561.6
            float loss_ce = (EOS_COEF * r0 + s0) / sum_w;
            float loss_t  = s1 / (float)(BB * NN);
            out[0] = loss_ce + TIME_WEIGHT * loss_t;
        }
    }
}

// ---------------------------------------------------------------------------
// Workspace layout (bytes):
//   [0,      25600)  : float logZ[6400]
//   [25600, 435200)  : float Cg[64*16*100]
//   [435200, 441600) : float lsepart[1600]
//   [441600, 441608) : float sums[2]   {ce_corr, time}   (zeroed by kernel 1)
//   [441608, 441612) : int   counter                     (zeroed by kernel 1)
// ---------------------------------------------------------------------------
extern "C" void kernel_launch(void* const* d_in, const int* in_sizes, int n_in,
                              void* d_out, int out_size, void* d_ws, size_t ws_size,
                              hipStream_t stream) {
    const float* logits = (const float*)d_in[0];   // [B,Q,2048]
    const float* ptime  = (const float*)d_in[1];   // [B,Q,1]
    const int*   labels = (const int*)d_in[2];     // [B,N]
    const float* tstamp = (const float*)d_in[3];   // [B,N,1]
    float* out = (float*)d_out;

    char* ws = (char*)d_ws;
    float* logZ    = (float*)ws;
    float* Cg      = (float*)(ws + 25600);
    float* lsepart = (float*)(ws + 435200);
    float* sums    = (float*)(ws + 441600);
    int*   counter = (int*)(ws + 441608);

    lse_cost_kernel<<<1600, 256, 0, stream>>>(logits, ptime, labels, tstamp,
                                              logZ, Cg, lsepart, sums, counter);
    hungarian_kernel<<<BB, 64, 0, stream>>>(Cg, logits, ptime, labels, tstamp,
                                            logZ, lsepart, sums, counter, out);
}